// Round 16
// baseline (169.956 us; speedup 1.0000x reference)
//
#include <hip/hip_runtime.h>

// B=4, S=2048, D=1024, H=16, HS=64. Full bf16-MFMA pipeline.
// Workspace layout (needs ~104 MiB):
//   Xb     @ 0         : x as bf16            [8192][1024]   16 MiB
//   WqkvT  @ 16777216  : qkv weights B^T bf16 [3072][1024]    6 MiB
//   WoT    @ 23068672  : Wo^T bf16            [1024][1024]    2 MiB
//   QKV    @ 25165824  : Q|K|V bf16           [8192][3072]   48 MiB
//   VT     @ 75497472  : V^T bf16, kappa-ordered keys  [64bh][64][2048] 16 MiB
//   AttnO  @ 92274688  : attention out bf16   [8192][1024]   16 MiB

typedef __bf16 bf16;
typedef bf16 bf16x8 __attribute__((ext_vector_type(8)));
typedef bf16 bf16x4 __attribute__((ext_vector_type(4)));
typedef float f32x4 __attribute__((ext_vector_type(4)));

__device__ __forceinline__ void gload16(const void* gsrc, void* ldst) {
  __builtin_amdgcn_global_load_lds(
      (const __attribute__((address_space(1))) unsigned int*)gsrc,
      (__attribute__((address_space(3))) unsigned int*)ldst, 16, 0, 0);
}

__device__ __forceinline__ f32x4 mfma16(bf16x8 a, bf16x8 b, f32x4 c) {
  return __builtin_amdgcn_mfma_f32_16x16x32_bf16(a, b, c, 0, 0, 0);
}

// ---------------- fused pack kernel (one launch) ----------------
__global__ __launch_bounds__(256) void pack_all_kernel(const float* __restrict__ x,
                                                       const float* __restrict__ Wq,
                                                       const float* __restrict__ Wk,
                                                       const float* __restrict__ Wv,
                                                       const float* __restrict__ Wo,
                                                       bf16* __restrict__ xb,
                                                       bf16* __restrict__ WT,
                                                       bf16* __restrict__ WoT) {
  const int stride = gridDim.x * 256;
  const int t0 = blockIdx.x * 256 + threadIdx.x;
  for (int i = t0; i < 2097152; i += stride) {
    float4 v = *(const float4*)(x + (size_t)i * 4);
    bf16x4 o;
    o[0] = (bf16)v.x; o[1] = (bf16)v.y; o[2] = (bf16)v.z; o[3] = (bf16)v.w;
    *(bf16x4*)(xb + (size_t)i * 4) = o;
  }
  for (int idx = t0; idx < 3145728; idx += stride) {
    int n = idx >> 10, k = idx & 1023;
    int sel = n >> 10, nn = n & 1023;
    const float* W = (sel == 0) ? Wq : (sel == 1 ? Wk : Wv);
    int h = nn >> 6, e = nn & 63;
    WT[(size_t)n * 1024 + k] = (bf16)W[h * 65536 + k * 64 + e];
  }
  for (int idx = t0; idx < 1048576; idx += stride) {
    int n = idx >> 10, k = idx & 1023;
    WoT[idx] = (bf16)Wo[k * 1024 + n];
  }
}

// ---------------- GEMM v4 (r12 best: 69.6us): C = A * BT^T ----------------
// Per-wave 64x64 (32 FLOP per LDS byte), BM=BN=128, BK=64, 256 threads
// (4 waves 2x2), 2 LDS slots (64KB) -> 2 blocks/CU. One barrier + one
// vmcnt(0) per K-tile. 3-bit XOR chunk swizzle. n-major-per-XCD mapping.
template <bool F32OUT>
__global__ __launch_bounds__(256, 2) void gemm4_kernel(const bf16* __restrict__ A,
                                                       const bf16* __restrict__ BT,
                                                       bf16* __restrict__ Cb,
                                                       float* __restrict__ Cf,
                                                       const float* __restrict__ bias,
                                                       int N, int K) {
  __shared__ bf16 As[2][128 * 64];  // [slot][row][k], chunk-swizzled
  __shared__ bf16 Bs[2][128 * 64];
  const int tid = threadIdx.x, lane = tid & 63, wave = tid >> 6;
  const int g = lane >> 4, c = lane & 15;
  const int wr = wave >> 1, wc = wave & 1;
  const int bid = blockIdx.x;
  const int xcd = bid & 7, local = bid >> 3;
  const int m0 = (xcd * 8 + (local & 7)) * 128;
  const int n0 = (local >> 3) * 128;

  const int schunk = (lane & 7) ^ (lane >> 3);  // source k-chunk for staging

#define STAGE4(T, S)                                                      \
  do {                                                                    \
    _Pragma("unroll") for (int j = 0; j < 4; ++j) {                       \
      const int r = wave * 32 + j * 8 + (lane >> 3);                      \
      const int ldso = wave * 4096 + j * 1024 + lane * 16;                \
      gload16(A + (size_t)(m0 + r) * K + (T)*64 + schunk * 8,             \
              (char*)&As[S][0] + ldso);                                   \
      gload16(BT + (size_t)(n0 + r) * K + (T)*64 + schunk * 8,            \
              (char*)&Bs[S][0] + ldso);                                   \
    }                                                                     \
  } while (0)

  f32x4 acc[4][4] = {};
  const int nt = K >> 6;  // K-tiles of 64
  STAGE4(0, 0);
  asm volatile("s_waitcnt vmcnt(0)" ::: "memory");
  __builtin_amdgcn_sched_barrier(0);
  __builtin_amdgcn_s_barrier();
  __builtin_amdgcn_sched_barrier(0);

#pragma unroll 1
  for (int t = 0; t < nt; ++t) {
    const int s = t & 1;
    if (t + 1 < nt) STAGE4(t + 1, s ^ 1);
    bf16x8 af[4][2], bfr[4][2];
#pragma unroll
    for (int m = 0; m < 4; ++m) {
      const int row = wr * 64 + m * 16 + c;
#pragma unroll
      for (int kk = 0; kk < 2; ++kk)
        af[m][kk] = *(const bf16x8*)((const char*)&As[s][0] + row * 128 +
                                     (((kk * 4 + g) ^ (row & 7)) << 4));
    }
#pragma unroll
    for (int n = 0; n < 4; ++n) {
      const int row = wc * 64 + n * 16 + c;
#pragma unroll
      for (int kk = 0; kk < 2; ++kk)
        bfr[n][kk] = *(const bf16x8*)((const char*)&Bs[s][0] + row * 128 +
                                      (((kk * 4 + g) ^ (row & 7)) << 4));
    }
    // no lgkm drain: compiler interleaves reads/MFMAs with counted lgkmcnt
    __builtin_amdgcn_s_setprio(1);
#pragma unroll
    for (int kk = 0; kk < 2; ++kk)
#pragma unroll
      for (int m = 0; m < 4; ++m)
#pragma unroll
        for (int n = 0; n < 4; ++n)
          acc[m][n] = mfma16(af[m][kk], bfr[n][kk], acc[m][n]);
    __builtin_amdgcn_s_setprio(0);
    if (t + 1 < nt) {
      asm volatile("s_waitcnt vmcnt(0)" ::: "memory");  // next slot landed
      __builtin_amdgcn_sched_barrier(0);
      __builtin_amdgcn_s_barrier();
      __builtin_amdgcn_sched_barrier(0);
    }
  }
#undef STAGE4
  // epilogue (r7-verified mapping)
#pragma unroll
  for (int m = 0; m < 4; ++m)
#pragma unroll
    for (int n = 0; n < 4; ++n)
#pragma unroll
      for (int i = 0; i < 4; ++i) {
        int row = m0 + wr * 64 + m * 16 + g * 4 + i;
        int col = n0 + wc * 64 + n * 16 + c;
        if (F32OUT)
          Cf[(size_t)row * N + col] = acc[m][n][i] + bias[col];
        else
          Cb[(size_t)row * N + col] = (bf16)acc[m][n][i];
      }
}

// ---------------- V transpose: VT[bh][d][pos] with kappa-ordered keys ------
__global__ __launch_bounds__(256) void transpose_v_kernel(const bf16* __restrict__ qkv,
                                                          bf16* __restrict__ vt) {
  __shared__ bf16 tl[64][72];  // stride 144B keeps 16B alignment for b128 stores
  const int tid = threadIdx.x;
  const int st = blockIdx.x, bh = blockIdx.y;
  const int b = bh >> 4, h = bh & 15;
#pragma unroll
  for (int it = 0; it < 2; ++it) {
    int idx = it * 256 + tid;          // 0..511
    int sl = idx >> 3, ch = idx & 7;   // sl 0..63 (s row), ch 0..7 (d chunk)
    bf16x8 v = *(const bf16x8*)(qkv + (size_t)(b * 2048 + st * 64 + sl) * 3072 + 2048 + h * 64 + ch * 8);
    *(bf16x8*)&tl[sl][ch * 8] = v;
  }
  __syncthreads();
#pragma unroll
  for (int it = 0; it < 2; ++it) {
    int idx = it * 256 + tid;
    int d = idx >> 3, ch = idx & 7;    // d 0..63, output chunk 0..7 (8 keys)
    const int blk = ch >> 2, g = ch & 3;  // 32-key block, frag group
    bf16x8 o;
#pragma unroll
    for (int j = 0; j < 8; ++j) {
      int loc = (j < 4) ? (4 * g + j) : (16 + 4 * g + (j - 4));  // kappa
      o[j] = tl[blk * 32 + loc][d];
    }
    *(bf16x8*)(vt + ((size_t)bh * 64 + d) * 2048 + st * 64 + ch * 8) = o;
  }
}

// ---------------- causal flash attention ----------------
// r16: attn was LDS-read-port-bound (16 resident waves x 32 b128 reads/tile
// ~ 2000-3000cy of a 3300cy tile; kf/vb frags are wave-independent so the
// traffic was 8x redundant). Restructure to 4 waves x 32 q-rows (m=0,1
// sub-tiles, the r4/r5-verified math): kf/vb read ONCE per wave, reused for
// both m -> LDS reads halve per CU; MFMA/VALU per wave double (those pipes
// had headroom). 256-thread blocks, grid 512, LDS 64KB -> 2 blocks/CU.
// Keeps: KVBLK=128, bh-major XCD map, kappa-ordered VT, tree-max, defer-max,
// single-barrier-per-tile skeleton.
__global__ __launch_bounds__(256, 2) void attn_kernel(const bf16* __restrict__ qkv,
                                                      const bf16* __restrict__ vt,
                                                      bf16* __restrict__ attn_out) {
  __shared__ bf16 Ks[2][128 * 64];   // [key][hd], chunk-swizzled, 16KB each
  __shared__ bf16 Vs[2][64 * 128];   // [d][kpos], chunk-swizzled, 16KB each
  const int tid = threadIdx.x, lane = tid & 63, wave = tid >> 6;
  const int g = lane >> 4, c = lane & 15;
  const int bid = blockIdx.x;
  const int xcd = bid & 7;
  const int x = (bid >> 3) & 7;
  const int bh = (bid >> 6) * 8 + xcd;
  const int b = bh >> 4, h = bh & 15;
  const float SCL = 0.125f * 1.4426950408889634f;  // log2(e) * scale

  bf16x8 ones;
#pragma unroll
  for (int j = 0; j < 8; ++j) ones[j] = (bf16)1.0f;

#define STAGE(KT, BUF)                                                                    \
  do {                                                                                    \
    _Pragma("unroll") for (int t2 = 0; t2 < 4; ++t2) {                                    \
      int o = t2 * 4096 + wave * 1024 + lane * 16; /* 0..16383 */                         \
      int rK = o >> 7, chK = (((o & 127) >> 4) ^ (rK & 7));                               \
      gload16((const char*)qkv +                                                          \
                  ((size_t)(b * 2048 + (KT)*128 + rK) * 3072 + 1024 + h * 64) * 2 +       \
                  (chK << 4),                                                             \
              (char*)Ks[BUF] + o);                                                        \
      int rV = o >> 8, chV = (((o & 255) >> 4) ^ (rV & 7));                               \
      gload16((const char*)vt + (((size_t)bh * 64 + rV) * 2048 + (KT)*128) * 2 +          \
                  (chV << 4),                                                             \
              (char*)Vs[BUF] + o);                                                        \
    }                                                                                     \
  } while (0)

#pragma unroll 1
  for (int ph = 0; ph < 2; ++ph) {
    const int qt = ph ? (15 - x) : x;
    const int qlow = qt * 128 + wave * 32;  // lowest q row of this wave (32 rows)

    bf16x8 qf[2][2];  // [m][kk]
#pragma unroll
    for (int m = 0; m < 2; ++m)
#pragma unroll
      for (int kk = 0; kk < 2; ++kk) {
        size_t row = (size_t)(b * 2048 + qlow + m * 16 + c);
        qf[m][kk] = *(const bf16x8*)(qkv + row * 3072 + h * 64 + kk * 32 + g * 8);
      }

    f32x4 oacc[2][4] = {};
    f32x4 lacc[2] = {};            // row-sums, oacc layout (q = .. + 4g+i)
    float mrun[2] = {-3.0e38f, -3.0e38f};  // per-lane: q = qlow + m*16 + c

    const int nkt = qt + 1;
    // phase prologue: protect buf0 from prev phase's last-tile readers,
    // then stage tile 0 and publish it.
    __builtin_amdgcn_s_barrier();
    __builtin_amdgcn_sched_barrier(0);
    STAGE(0, 0);
    asm volatile("s_waitcnt vmcnt(0)" ::: "memory");
    __builtin_amdgcn_sched_barrier(0);
    __builtin_amdgcn_s_barrier();
    __builtin_amdgcn_sched_barrier(0);
    for (int kt = 0; kt < nkt; ++kt) {
      const int cur = kt & 1;
      if (kt + 1 < nkt) STAGE(kt + 1, cur ^ 1);
      // QK^T swapped: sc[n][m] holds S[key=kt*128+n*16+4g+i][q=qlow+m*16+c]
      f32x4 sc[8][2] = {};
      __builtin_amdgcn_s_setprio(1);
#pragma unroll
      for (int n = 0; n < 8; ++n) {
        int key = n * 16 + c;
#pragma unroll
        for (int kk = 0; kk < 2; ++kk) {
          bf16x8 kf = *(const bf16x8*)((const char*)Ks[cur] + key * 128 +
                                       (((kk * 4 + g) ^ (key & 7)) << 4));
#pragma unroll
          for (int m = 0; m < 2; ++m) sc[n][m] = mfma16(kf, qf[m][kk], sc[n][m]);
        }
      }
      __builtin_amdgcn_s_setprio(0);
      float mx[2];
#pragma unroll
      for (int m = 0; m < 2; ++m) {
        const int q = qlow + m * 16 + c;
        if (kt == qt) {  // diagonal tile: causal mask
#pragma unroll
          for (int n = 0; n < 8; ++n)
#pragma unroll
            for (int i = 0; i < 4; ++i)
              sc[n][m][i] = ((kt * 128 + n * 16 + 4 * g + i) <= q) ? sc[n][m][i] : -3.0e38f;
        }
        // tree max
        float a[8];
#pragma unroll
        for (int n = 0; n < 8; ++n)
          a[n] = fmaxf(fmaxf(sc[n][m][0], sc[n][m][1]), fmaxf(sc[n][m][2], sc[n][m][3]));
        float b0 = fmaxf(a[0], a[1]), b1 = fmaxf(a[2], a[3]);
        float b2 = fmaxf(a[4], a[5]), b3 = fmaxf(a[6], a[7]);
        float vmax = fmaxf(fmaxf(b0, b1), fmaxf(b2, b3));
        vmax = fmaxf(vmax, __shfl_xor(vmax, 16));
        vmax = fmaxf(vmax, __shfl_xor(vmax, 32));
        mx[m] = vmax * SCL;
      }
      // defer-max (T13): rescale only when some row's max grew by >8 (log2)
      if (!__all(mx[0] <= mrun[0] + 8.0f && mx[1] <= mrun[1] + 8.0f)) {
#pragma unroll
        for (int m = 0; m < 2; ++m) {
          const float mnew = fmaxf(mrun[m], mx[m]);
          const float fs = __builtin_amdgcn_exp2f(mrun[m] - mnew);
          mrun[m] = mnew;
#pragma unroll
          for (int i = 0; i < 4; ++i) {
            float fsb = __shfl(fs, ((lane >> 4) << 2) + i);
            lacc[m][i] *= fsb;
#pragma unroll
            for (int dn = 0; dn < 4; ++dn) oacc[m][dn][i] *= fsb;
          }
        }
      }
#pragma unroll
      for (int m = 0; m < 2; ++m)
#pragma unroll
        for (int n = 0; n < 8; ++n)
#pragma unroll
          for (int i = 0; i < 4; ++i)
            sc[n][m][i] = __builtin_amdgcn_exp2f(fmaf(sc[n][m][i], SCL, -mrun[m]));
      // pack PV A-frags: key = kss*32 + (j<4 ? 4g+j : 16+4g+(j-4))
      bf16x8 pa[2][4];
#pragma unroll
      for (int m = 0; m < 2; ++m)
#pragma unroll
        for (int kss = 0; kss < 4; ++kss) {
          bf16x8 t;
#pragma unroll
          for (int j = 0; j < 4; ++j) t[j] = (bf16)sc[2 * kss][m][j];
#pragma unroll
          for (int j = 0; j < 4; ++j) t[4 + j] = (bf16)sc[2 * kss + 1][m][j];
          pa[m][kss] = t;
        }
      // PV + row-sum via ones-MFMA; vb read once per (kss,dn), reused for both m
      __builtin_amdgcn_s_setprio(1);
#pragma unroll
      for (int kss = 0; kss < 4; ++kss) {
#pragma unroll
        for (int m = 0; m < 2; ++m) lacc[m] = mfma16(pa[m][kss], ones, lacc[m]);
#pragma unroll
        for (int dn = 0; dn < 4; ++dn) {
          const int d = dn * 16 + c;
          bf16x8 vb = *(const bf16x8*)((const char*)Vs[cur] + d * 256 +
                                       (((kss * 4 + g) ^ (d & 7)) << 4));
#pragma unroll
          for (int m = 0; m < 2; ++m) oacc[m][dn] = mfma16(pa[m][kss], vb, oacc[m][dn]);
        }
      }
      __builtin_amdgcn_s_setprio(0);
      if (kt + 1 < nkt) {
        asm volatile("s_waitcnt vmcnt(0)" ::: "memory");  // kt+1 landed (issued ~1 tile ago)
        __builtin_amdgcn_sched_barrier(0);
        __builtin_amdgcn_s_barrier();  // publish kt+1; readers of cur done
        __builtin_amdgcn_sched_barrier(0);
      }
    }
    // epilogue: normalize, store bf16 [8192][1024]
#pragma unroll
    for (int m = 0; m < 2; ++m)
#pragma unroll
      for (int i = 0; i < 4; ++i) {
        float inv = __builtin_amdgcn_rcpf(lacc[m][i]);
        size_t row = (size_t)(b * 2048 + qlow + m * 16 + 4 * g + i);
#pragma unroll
        for (int dn = 0; dn < 4; ++dn)
          attn_out[row * 1024 + h * 64 + dn * 16 + c] = (bf16)(oacc[m][dn][i] * inv);
      }
  }
#undef STAGE
}

// ---------------- launch ----------------
extern "C" void kernel_launch(void* const* d_in, const int* in_sizes, int n_in,
                              void* d_out, int out_size, void* d_ws, size_t ws_size,
                              hipStream_t stream) {
  const float* x  = (const float*)d_in[0];
  const float* Wq = (const float*)d_in[1];
  const float* Wk = (const float*)d_in[2];
  const float* Wv = (const float*)d_in[3];
  const float* Wo = (const float*)d_in[4];
  const float* bo = (const float*)d_in[5];
  float* out = (float*)d_out;
  char* ws = (char*)d_ws;

  bf16* Xb    = (bf16*)(ws);
  bf16* WqkvT = (bf16*)(ws + 16777216);
  bf16* WoT   = (bf16*)(ws + 23068672);
  bf16* QKV   = (bf16*)(ws + 25165824);
  bf16* VT    = (bf16*)(ws + 75497472);
  bf16* AttnO = (bf16*)(ws + 92274688);

  pack_all_kernel<<<2048, 256, 0, stream>>>(x, Wq, Wk, Wv, Wo, Xb, WqkvT, WoT);
  gemm4_kernel<false><<<1536, 256, 0, stream>>>(Xb, WqkvT, QKV, nullptr, nullptr,
                                                3072, 1024);
  transpose_v_kernel<<<dim3(32, 64), 256, 0, stream>>>(QKV, VT);
  attn_kernel<<<512, 256, 0, stream>>>(QKV, VT, AttnO);
  gemm4_kernel<true><<<512, 256, 0, stream>>>(AttnO, WoT, nullptr, out, bo,
                                              1024, 1024);
}